// Round 3
// baseline (765.415 us; speedup 1.0000x reference)
//
#include <hip/hip_runtime.h>

#define NTRAIN 32768
#define NTEST  4096
#define DIM    64
#define KSEL   32
#define NLAB   1000

#define SPRE   2048   // sample size for threshold (first SPRE train points)
#define PRANK  16     // threshold rank within sample -> E[cnt] ~ 256
#define PTB    8      // tests per pre block
#define CAP    768    // candidate capacity per test
#define TB     16     // tests per knnA block
#define CHUNK  2048   // train cols per knnA block
#define POOLCAP 1600

// monotone float -> uint mapping (preserves total order incl. negatives)
__device__ __forceinline__ unsigned f2u(float f){
  unsigned b = __float_as_uint(f);
  return (b & 0x80000000u) ? ~b : (b | 0x80000000u);
}

struct Sel {
  unsigned hist[2048];
  unsigned wsum[4];
  unsigned sB, sLess, sU;
  int sNeed;
};

// exact value of the rank-th smallest key (1-based) among keys[0..n). n>=rank.
// 4 barriers/level via wave-shuffle scan (vs 20 for Hillis-Steele).
__device__ unsigned radix_select(const unsigned* __restrict__ keys, int n,
                                 unsigned rank, Sel* s, int t, int* needOut)
{
  const int lane = t & 63, wid = t >> 6;
  unsigned target = rank, pref = 0;
  for (int lev = 0; lev < 3; ++lev){
    const int nb    = (lev == 2) ? 1024 : 2048;
    const int shift = (lev == 0) ? 21 : (lev == 1 ? 10 : 0);
    for (int q = t; q < nb; q += 256) s->hist[q] = 0;
    __syncthreads();
    for (int i = t; i < n; i += 256){
      unsigned u = keys[i];
      bool ok = (lev == 0) ? true
              : (lev == 1) ? ((u >> 21) == pref)
                           : ((u >> 10) == pref);
      if (ok) atomicAdd(&s->hist[(u >> shift) & (unsigned)(nb - 1)], 1u);
    }
    __syncthreads();
    const int g = nb / 256;
    unsigned sl = 0;
#pragma unroll
    for (int k = 0; k < 8; ++k) if (k < g) sl += s->hist[t*g + k];
    unsigned x = sl;
#pragma unroll
    for (int ofs = 1; ofs < 64; ofs <<= 1){
      unsigned v = __shfl_up(x, (unsigned)ofs, 64);
      if (lane >= ofs) x += v;
    }
    if (lane == 63) s->wsum[wid] = x;
    __syncthreads();
    unsigned woff = 0;
#pragma unroll
    for (int w = 0; w < 4; ++w) if (w < wid) woff += s->wsum[w];
    unsigned incl = x + woff;
    unsigned excl = incl - sl;
    if (excl < target && target <= incl){
      unsigned cum = excl; int b = t*g;
      while (cum + s->hist[b] < target){ cum += s->hist[b]; ++b; }
      s->sB = (unsigned)b; s->sLess = cum;
    }
    __syncthreads();
    unsigned B = s->sB, cl = s->sLess;
    target -= cl;
    if      (lev == 0) pref = B;
    else if (lev == 1) pref = (pref << 11) | B;
    else if (t == 0){ s->sU = (pref << 10) | B; s->sNeed = (int)target; }
  }
  __syncthreads();
  *needOut = s->sNeed;
  return s->sU;
}

// exact top-KSEL among (ku,ki)[0..n) by (key asc, idx asc). n>=KSEL. writes selI.
__device__ void select32(const unsigned* ku, const unsigned* ki, int n,
                         Sel* s, unsigned* tieI, unsigned* selI,
                         int* selCnt, int* tieCnt, int t)
{
  int need;
  unsigned ustar = radix_select(ku, n, KSEL, s, t, &need);
  if (t == 0){ *selCnt = 0; *tieCnt = 0; }
  __syncthreads();
  for (int i = t; i < n; i += 256){
    unsigned u = ku[i];
    if (u < ustar){ int p = atomicAdd(selCnt, 1); if (p < 40) selI[p] = ki[i]; }
    else if (u == ustar){ int p = atomicAdd(tieCnt, 1); if (p < 256) tieI[p] = ki[i]; }
  }
  __syncthreads();
  int nT = *tieCnt; if (nT > 256) nT = 256;
  if (t < nT){
    unsigned my = tieI[t]; int r = 0;
    for (int k = 0; k < nT; ++k) r += (tieI[k] < my) ? 1 : 0;
    if (r < need){ int p = atomicAdd(selCnt, 1); if (p < 40) selI[p] = my; }
  }
  __syncthreads();
}

// ---- prep: xT[d][j] column-major transpose + b2 ----
__global__ __launch_bounds__(256) void prep(const float* __restrict__ xtr,
                                            float* __restrict__ xT,
                                            float* __restrict__ b2)
{
  int j = blockIdx.x*256 + threadIdx.x;
  const float4* rp = (const float4*)(xtr + (size_t)j * DIM);
  float v[DIM]; float s = 0.f;
#pragma unroll
  for (int q = 0; q < 16; ++q){
    float4 w = rp[q];
    v[4*q]=w.x; v[4*q+1]=w.y; v[4*q+2]=w.z; v[4*q+3]=w.w;
    s = fmaf(w.x,w.x,s); s = fmaf(w.y,w.y,s); s = fmaf(w.z,w.z,s); s = fmaf(w.w,w.w,s);
  }
#pragma unroll
  for (int d = 0; d < DIM; ++d) xT[(size_t)d*NTRAIN + j] = v[d];
  b2[j] = s;
}

// ---- pre: per-test threshold = PRANK-th smallest key over first SPRE train pts ----
__global__ __launch_bounds__(256) void pre_kernel(const float* __restrict__ xT,
        const float* __restrict__ b2, const float* __restrict__ x_test,
        unsigned* __restrict__ Tu)
{
  __shared__ float As[DIM][PTB];        // 2 KB
  __shared__ unsigned keys[PTB][SPRE];  // 64 KB
  __shared__ Sel ss;

  const int t = threadIdx.x;
  const int m0 = blockIdx.x * PTB;

  for (int i = t; i < PTB*DIM; i += 256){
    int r = i & (PTB-1), d = i >> 3;
    As[d][r] = x_test[(size_t)(m0 + r)*DIM + d];
  }
  __syncthreads();

  float acc[PTB][8];
#pragma unroll
  for (int r = 0; r < PTB; ++r)
#pragma unroll
    for (int c = 0; c < 8; ++c) acc[r][c] = 0.f;

#pragma unroll 2
  for (int d = 0; d < DIM; ++d){
    const float* bp = xT + (size_t)d*NTRAIN + t*8;
    float4 b0 = *(const float4*)bp;
    float4 b1 = *(const float4*)(bp + 4);
    float bv[8] = {b0.x,b0.y,b0.z,b0.w,b1.x,b1.y,b1.z,b1.w};
    float4 a0 = *(const float4*)&As[d][0];
    float4 a1 = *(const float4*)&As[d][4];
    float av[8] = {a0.x,a0.y,a0.z,a0.w,a1.x,a1.y,a1.z,a1.w};
#pragma unroll
    for (int r = 0; r < PTB; ++r)
#pragma unroll
      for (int c = 0; c < 8; ++c)
        acc[r][c] = fmaf(av[r], bv[c], acc[r][c]);
  }

  float4 q0 = *(const float4*)&b2[t*8];
  float4 q1 = *(const float4*)&b2[t*8 + 4];
  float b2v[8] = {q0.x,q0.y,q0.z,q0.w,q1.x,q1.y,q1.z,q1.w};
#pragma unroll
  for (int r = 0; r < PTB; ++r){
    uint4 u0, u1;
    u0.x = f2u(fmaf(-2.f, acc[r][0], b2v[0]));
    u0.y = f2u(fmaf(-2.f, acc[r][1], b2v[1]));
    u0.z = f2u(fmaf(-2.f, acc[r][2], b2v[2]));
    u0.w = f2u(fmaf(-2.f, acc[r][3], b2v[3]));
    u1.x = f2u(fmaf(-2.f, acc[r][4], b2v[4]));
    u1.y = f2u(fmaf(-2.f, acc[r][5], b2v[5]));
    u1.z = f2u(fmaf(-2.f, acc[r][6], b2v[6]));
    u1.w = f2u(fmaf(-2.f, acc[r][7], b2v[7]));
    *(uint4*)&keys[r][t*8]     = u0;
    *(uint4*)&keys[r][t*8 + 4] = u1;
  }
  __syncthreads();

  for (int r = 0; r < PTB; ++r){
    int need;
    unsigned ustar = radix_select(&keys[r][0], SPRE, PRANK, &ss, t, &need);
    if (t == 0) Tu[m0 + r] = ustar;
  }
}

// ---- kernel A: barrier-free register-B key GEMM + threshold filter ----
__global__ __launch_bounds__(256) void knnA(const float* __restrict__ xT,
        const float* __restrict__ b2, const float* __restrict__ x_test,
        const unsigned* __restrict__ Tu, unsigned* __restrict__ cnt,
        unsigned* __restrict__ cand)
{
  __shared__ float As[DIM][TB];   // 4 KB, read as same-address broadcast
  __shared__ unsigned Ts[TB];

  const int t = threadIdx.x;
  // XCD-aware swizzle: same chunk -> same (presumed) XCD so the 512 KB
  // chunk stays L2-resident across its 256 test-group blocks.
  const int bid  = blockIdx.x;
  const int g    = bid & 7;
  const int sgrp = bid >> 3;
  const int chunkI = g + 8*(sgrp & 1);
  const int mgrp   = sgrp >> 1;
  const int m0 = mgrp * TB;
  const int c0 = chunkI * CHUNK;

  for (int i = t; i < TB*DIM; i += 256){
    int r = i & (TB-1), d = i >> 4;
    As[d][r] = x_test[(size_t)(m0 + r)*DIM + d];
  }
  if (t < TB) Ts[t] = Tu[m0 + t];
  __syncthreads();   // the ONLY barrier in this kernel

  float acc[TB][8];
#pragma unroll
  for (int r = 0; r < TB; ++r)
#pragma unroll
    for (int c = 0; c < 8; ++c) acc[r][c] = 0.f;

  const float* B = xT + c0 + t*8;
#pragma unroll 2
  for (int d = 0; d < DIM; ++d){
    float4 b0 = *(const float4*)(B + (size_t)d*NTRAIN);
    float4 b1 = *(const float4*)(B + (size_t)d*NTRAIN + 4);
    float bv[8] = {b0.x,b0.y,b0.z,b0.w,b1.x,b1.y,b1.z,b1.w};
    float4 a0 = *(const float4*)&As[d][0];
    float4 a1 = *(const float4*)&As[d][4];
    float4 a2 = *(const float4*)&As[d][8];
    float4 a3 = *(const float4*)&As[d][12];
    float av[16] = {a0.x,a0.y,a0.z,a0.w,a1.x,a1.y,a1.z,a1.w,
                    a2.x,a2.y,a2.z,a2.w,a3.x,a3.y,a3.z,a3.w};
#pragma unroll
    for (int r = 0; r < TB; ++r)
#pragma unroll
      for (int c = 0; c < 8; ++c)
        acc[r][c] = fmaf(av[r], bv[c], acc[r][c]);
  }

  float4 q0 = *(const float4*)&b2[c0 + t*8];
  float4 q1 = *(const float4*)&b2[c0 + t*8 + 4];
  float b2v[8] = {q0.x,q0.y,q0.z,q0.w,q1.x,q1.y,q1.z,q1.w};
#pragma unroll
  for (int r = 0; r < TB; ++r){
    unsigned thr = Ts[r];
    int mrow = m0 + r;
#pragma unroll
    for (int c = 0; c < 8; ++c){
      unsigned u = f2u(fmaf(-2.f, acc[r][c], b2v[c]));
      if (u < thr){
        unsigned p = atomicAdd(&cnt[mrow], 1u);
        if (p < CAP) cand[(size_t)mrow*CAP + p] = (unsigned)(c0 + t*8 + c);
      }
    }
  }
}

// ---- kernel B: exact top-32 among candidates (or full-scan fallback), vote, argmax ----
__global__ __launch_bounds__(256) void knnB(const float* __restrict__ x_train,
        const float* __restrict__ xT, const float* __restrict__ b2,
        const float* __restrict__ x_test, const int* __restrict__ y_train,
        const float* __restrict__ w_train, const unsigned* __restrict__ cnt,
        const unsigned* __restrict__ cand, int* __restrict__ out)
{
  __shared__ unsigned ku[POOLCAP], ki[POOLCAP];
  __shared__ unsigned chunkKeys[1024];
  __shared__ Sel ss;
  __shared__ unsigned tieI[256];
  __shared__ unsigned selI[40];
  __shared__ int selCnt, tieCnt, poolCnt;
  __shared__ float votes[NLAB];

  const int t = threadIdx.x, m = blockIdx.x;
  float a[DIM];
  const float* am = x_test + (size_t)m*DIM;
#pragma unroll
  for (int d = 0; d < DIM; ++d) a[d] = am[d];

  unsigned c = cnt[m];
  if (c >= KSEL && c <= CAP){
    // main path: recompute exact keys for candidates
    for (int i = t; i < (int)c; i += 256){
      unsigned j = cand[(size_t)m*CAP + i];
      const float4* rp = (const float4*)(x_train + (size_t)j*DIM);
      float s = 0.f;
#pragma unroll
      for (int q = 0; q < 16; ++q){
        float4 w = rp[q];
        s = fmaf(a[4*q],w.x,s); s = fmaf(a[4*q+1],w.y,s);
        s = fmaf(a[4*q+2],w.z,s); s = fmaf(a[4*q+3],w.w,s);
      }
      ku[i] = f2u(fmaf(-2.f, s, b2[j]));
      ki[i] = j;
    }
    __syncthreads();
    select32(ku, ki, (int)c, &ss, tieI, selI, &selCnt, &tieCnt, t);
  } else {
    // fallback (astronomically rare): exact full scan, pool chunk-top-32s
    if (t == 0) poolCnt = 0;
    __syncthreads();
    for (int ch = 0; ch < NTRAIN/1024; ++ch){
      const int j0 = ch*1024;
      for (int q = 0; q < 4; ++q){
        int jj = q*256 + t;
        float s = 0.f;
#pragma unroll
        for (int d = 0; d < DIM; ++d) s = fmaf(a[d], xT[(size_t)d*NTRAIN + j0 + jj], s);
        chunkKeys[jj] = f2u(fmaf(-2.f, s, b2[j0 + jj]));
      }
      __syncthreads();
      int need;
      unsigned ustar = radix_select(chunkKeys, 1024, KSEL, &ss, t, &need);
      for (int q = 0; q < 4; ++q){
        int jj = q*256 + t;
        unsigned u = chunkKeys[jj];
        if (u <= ustar){
          int p = atomicAdd(&poolCnt, 1);
          if (p < POOLCAP){ ku[p] = u; ki[p] = (unsigned)(j0 + jj); }
        }
      }
      __syncthreads();
    }
    int n = poolCnt; if (n > POOLCAP) n = POOLCAP;
    select32(ku, ki, n, &ss, tieI, selI, &selCnt, &tieCnt, t);
  }

  // weighted vote over 1000 labels
  for (int q = t; q < NLAB; q += 256) votes[q] = 0.f;
  __syncthreads();
  int nSel = selCnt; if (nSel > KSEL) nSel = KSEL;
  if (t < nSel){
    unsigned j = selI[t];
    atomicAdd(&votes[y_train[j]], w_train[j]);
  }
  __syncthreads();

  // argmax, lowest label wins ties
  float* rv = (float*)ss.hist;
  int*   rl = (int*)(ss.hist + 256);
  float bv = -1.f; int bl = 0;
  for (int l = t; l < NLAB; l += 256){
    float v = votes[l];
    if (v > bv){ bv = v; bl = l; }
  }
  rv[t] = bv; rl[t] = bl;
  __syncthreads();
  for (int sred = 128; sred > 0; sred >>= 1){
    if (t < sred){
      if (rv[t+sred] > rv[t] || (rv[t+sred] == rv[t] && rl[t+sred] < rl[t])){
        rv[t] = rv[t+sred]; rl[t] = rl[t+sred];
      }
    }
    __syncthreads();
  }
  if (t == 0) out[m] = rl[0];
}

// ---- legacy (round-1, direct-read path): used only if ws too small ----
__global__ __launch_bounds__(256) void knn_legacy(
    const float* __restrict__ x_train, const float* __restrict__ x_test,
    const int* __restrict__ y_train, const float* __restrict__ w_train,
    int* __restrict__ out)
{
  __shared__ unsigned keys[16384];
  __shared__ Sel ss;
  __shared__ unsigned candU[64];
  __shared__ unsigned candI[64];
  __shared__ unsigned tieI[256];
  __shared__ int nCand, nTie;
  __shared__ float rv[256]; __shared__ int rl[256];

  float* votes = (float*)ss.hist;
  const int t = threadIdx.x;
  const int m = blockIdx.x;

  float a[DIM];
  const float* am = x_test + (size_t)m * DIM;
#pragma unroll
  for (int d = 0; d < DIM; ++d) a[d] = am[d];

  if (t == 0) nCand = 0;

  for (int h = 0; h < 2; ++h){
    __syncthreads();
    for (int i = 0; i < 64; ++i){
      int j = h*16384 + i*256 + t;
      const float4* bp = (const float4*)(x_train + (size_t)j * DIM);
      float s = 0.f;
#pragma unroll
      for (int q = 0; q < 16; ++q){
        float4 v = bp[q];
        float e0 = a[4*q]   - v.x, e1 = a[4*q+1] - v.y;
        float e2 = a[4*q+2] - v.z, e3 = a[4*q+3] - v.w;
        s = fmaf(e0,e0,s); s = fmaf(e1,e1,s); s = fmaf(e2,e2,s); s = fmaf(e3,e3,s);
      }
      keys[i*256 + t] = f2u(s);
    }
    __syncthreads();

    int need;
    unsigned ustar = radix_select(keys, 16384, KSEL, &ss, t, &need);
    if (t == 0) nTie = 0;
    __syncthreads();

    for (int i = 0; i < 64; ++i){
      unsigned u   = keys[i*256 + t];
      unsigned idx = (unsigned)(h*16384 + i*256 + t);
      if (u < ustar){
        int p = atomicAdd(&nCand, 1);
        if (p < 64){ candU[p] = u; candI[p] = idx; }
      } else if (u == ustar){
        int p = atomicAdd(&nTie, 1);
        if (p < 256) tieI[p] = idx;
      }
    }
    __syncthreads();
    int nT = nTie; if (nT > 256) nT = 256;
    if (t < nT){
      unsigned my = tieI[t]; int r = 0;
      for (int k = 0; k < nT; ++k) r += (tieI[k] < my) ? 1 : 0;
      if (r < need){
        int p = atomicAdd(&nCand, 1);
        if (p < 64){ candU[p] = ustar; candI[p] = my; }
      }
    }
    __syncthreads();
  }

  for (int q = t; q < NLAB; q += 256) votes[q] = 0.f;
  __syncthreads();
  int nC = nCand; if (nC > 64) nC = 64;
  if (t < nC){
    unsigned mu = candU[t], mi = candI[t];
    int r = 0;
    for (int k = 0; k < nC; ++k){
      unsigned kku = candU[k], kki = candI[k];
      r += (kku < mu || (kku == mu && kki < mi)) ? 1 : 0;
    }
    if (r < KSEL){
      int lab = y_train[mi];
      atomicAdd(&votes[lab], w_train[mi]);
    }
  }
  __syncthreads();

  float bv = -1.f; int bl = 0;
  for (int l = t; l < NLAB; l += 256){
    float v = votes[l];
    if (v > bv){ bv = v; bl = l; }
  }
  rv[t] = bv; rl[t] = bl;
  __syncthreads();
  for (int s = 128; s > 0; s >>= 1){
    if (t < s){
      if (rv[t+s] > rv[t] || (rv[t+s] == rv[t] && rl[t+s] < rl[t])){
        rv[t] = rv[t+s]; rl[t] = rl[t+s];
      }
    }
    __syncthreads();
  }
  if (t == 0) out[m] = rl[0];
}

extern "C" void kernel_launch(void* const* d_in, const int* in_sizes, int n_in,
                              void* d_out, int out_size, void* d_ws, size_t ws_size,
                              hipStream_t stream)
{
  (void)in_sizes; (void)n_in; (void)out_size;
  const float* x_train = (const float*)d_in[0];
  const int*   y_train = (const int*)  d_in[1];
  const float* x_test  = (const float*)d_in[2];
  const float* w_train = (const float*)d_in[3];
  int* out = (int*)d_out;

  const size_t need = ((size_t)NTRAIN*DIM + NTRAIN + NTEST + NTEST
                       + (size_t)NTEST*CAP) * sizeof(float);
  if (ws_size >= need){
    float* xT = (float*)d_ws;
    float* b2 = xT + (size_t)NTRAIN*DIM;
    unsigned* Tu   = (unsigned*)(b2 + NTRAIN);
    unsigned* cnt  = Tu + NTEST;
    unsigned* cand = cnt + NTEST;
    prep<<<NTRAIN/256, 256, 0, stream>>>(x_train, xT, b2);
    pre_kernel<<<NTEST/PTB, 256, 0, stream>>>(xT, b2, x_test, Tu);
    hipMemsetAsync(cnt, 0, NTEST*sizeof(unsigned), stream);
    knnA<<<(NTEST/TB)*(NTRAIN/CHUNK), 256, 0, stream>>>(xT, b2, x_test, Tu, cnt, cand);
    knnB<<<NTEST, 256, 0, stream>>>(x_train, xT, b2, x_test, y_train, w_train,
                                    cnt, cand, out);
  } else {
    knn_legacy<<<NTEST, 256, 0, stream>>>(x_train, x_test, y_train, w_train, out);
  }
}